// Round 13
// baseline (2692.518 us; speedup 1.0000x reference)
//
#include <hip/hip_runtime.h>
#include <math.h>

#define BATCH 4
#define NN 4096
#define DIN 128
#define DE 64
#define KK 16
#define CAP 128
#define GMAXF 2.9135f   // rigorous upper bound on f32 G = log(-log(q+1e-8))
#define GMINPAD 16.65f  // rigorous: G > -16.64 => lq_i < P_i + 16.64
#define SCRMARG 0.01f   // f32 rounding slack on the screen compare

// ---------------- K1: xe = x @ W + bias (r7-verified golden replica) ----------------
__global__ __launch_bounds__(256) void embed_kernel(
    const float* __restrict__ x, const float* __restrict__ W,
    const float* __restrict__ bias, float* __restrict__ xe) {
#pragma clang fp contract(off)
  __shared__ float wl[DIN][DE];
  __shared__ float xs[4][DIN];
  int t = threadIdx.x;
  for (int i = t * 4; i < DIN * DE; i += 1024)
    *(float4*)&wl[i >> 6][i & 63] = *(const float4*)&W[i];
  {
    int rr = t >> 6, dd = (t & 63) * 2;
    const float* src = x + ((size_t)blockIdx.x * 4 + rr) * DIN + dd;
    xs[rr][dd] = src[0];
    xs[rr][dd + 1] = src[1];
  }
  __syncthreads();
  int w = t >> 6, lane = t & 63;
  float acc = 0.f;
#pragma unroll
  for (int d = 0; d < DIN; ++d)
    acc = __builtin_fmaf(xs[w][d], wl[d][lane], acc);  // sequential FMA chain
  xe[((size_t)blockIdx.x * 4 + w) * DE + lane] = acc + bias[lane];
}

// numpy pairwise sum (n=64, scalar 8-accumulator path) of squares (r7-verified)
static __device__ __forceinline__ float np_pairwise_sq64(const float* a) {
#pragma clang fp contract(off)
  float p[8];
#pragma unroll
  for (int j = 0; j < 8; ++j) { float v = a[j]; p[j] = v * v; }
#pragma unroll
  for (int i = 8; i < 64; i += 8)
#pragma unroll
    for (int j = 0; j < 8; ++j) { float v = a[i + j]; p[j] = p[j] + v * v; }
  return ((p[0] + p[1]) + (p[2] + p[3])) + ((p[4] + p[5]) + (p[6] + p[7]));
}

// ---------------- K2: squared norms ----------------
__global__ __launch_bounds__(256) void sqnorm_kernel(
    const float* __restrict__ xe, float* __restrict__ sq) {
  int row = blockIdx.x * 256 + threadIdx.x;
  sq[row] = np_pairwise_sq64(xe + (size_t)row * DE);
}

// ---------------- K2b: xeT[b][d][c] = xe[b][c][d] ----------------
__global__ __launch_bounds__(256) void transpose_kernel(
    const float* __restrict__ xe, float* __restrict__ xeT) {
  int g = (int)blockIdx.x * 256 + (int)threadIdx.x;  // global row
  int b = g >> 12, cc = g & (NN - 1);
  const float* src = xe + (size_t)g * DE;
  float* dst = xeT + (size_t)b * DE * NN + cc;
#pragma unroll
  for (int j = 0; j < DE / 4; ++j) {
    float4 v = ((const float4*)src)[j];
    dst[(size_t)(4 * j + 0) * NN] = v.x;
    dst[(size_t)(4 * j + 1) * NN] = v.y;
    dst[(size_t)(4 * j + 2) * NN] = v.z;
    dst[(size_t)(4 * j + 3) * NN] = v.w;
  }
}

// ---------------- K3/K5: SMEM-B GEMM pass ----------------
// Block = 64 rows x 1024 cols. Wave w: all 64 rows x 16 uniform cols per iter.
// Lane owns 1 row. Per d: 1 ds_read_b32 (A) + s_load_dwordx16 (B, scalar pipe)
// + 16 v_fmac(vgpr,sgpr). Zero syncs in hot loop. Math bit-identical to r12.
template <bool PASSB>
__global__ __launch_bounds__(256) void gemm_pass_kernel(
    const float* __restrict__ xe, const float* __restrict__ xeT,
    const float* __restrict__ sq, const float* __restrict__ temp,
    float2* __restrict__ cellmin, const float* __restrict__ thrP,
    int* __restrict__ cnt, float* __restrict__ candP,
    unsigned short* __restrict__ candC) {
#pragma clang fp contract(off)
  __shared__ float At[DE * 64];  // 16 KB, [d][r]
  int t = threadIdx.x;
  int w = __builtin_amdgcn_readfirstlane(t >> 6);
  int lane = t & 63;
  int bid = (int)blockIdx.x;
  int rb = bid >> 2;      // row-block 0..255
  int colseg = bid & 3;   // 1024-col segment
  int b = rb >> 6;        // batch (uniform)
  int grow = rb * 64 + lane;   // global row
  int n = grow & (NN - 1);     // row within batch

  {  // stage At: wave w stages d-range [w*16, w*16+16) for all 64 rows
    const float* src = xe + (size_t)(rb * 64 + lane) * DE + w * 16;
#pragma unroll
    for (int j = 0; j < 4; ++j) {
      float4 v = ((const float4*)src)[j];
      int d = w * 16 + 4 * j;
      At[(d + 0) * 64 + lane] = v.x;
      At[(d + 1) * 64 + lane] = v.y;
      At[(d + 2) * 64 + lane] = v.z;
      At[(d + 3) * 64 + lane] = v.w;
    }
  }
  __syncthreads();

  float sqr = sq[grow];
  double tc = (double)temp[0];
  float s32 = (float)exp(fmin(fmax(tc, -5.0), 5.0));
  float thrv = 0.f;
  if (PASSB) thrv = thrP[grow] + SCRMARG;

  const float* BT = xeT + (size_t)b * DE * NN;  // uniform
  const float* sqb = sq + (b << 12);            // uniform

  float mn1 = __builtin_inff(), mn2 = __builtin_inff();

  for (int ci = 0; ci < 16; ++ci) {
    int c0 = colseg * 1024 + ci * 64 + w * 16;  // uniform
    float acc[16];
#pragma unroll
    for (int c = 0; c < 16; ++c) acc[c] = 0.f;
#pragma unroll
    for (int d = 0; d < DE; ++d) {  // d ascending: golden seq-FMA order
      float a = At[d * 64 + lane];
      const float* brow = BT + (size_t)d * NN + c0;  // uniform -> s_load
#pragma unroll
      for (int c = 0; c < 16; ++c)
        acc[c] = __builtin_fmaf(a, brow[c], acc[c]);
    }
    const float* sc = sqb + c0;  // uniform
#pragma unroll
    for (int c = 0; c < 16; ++c) {
      float u = (sqr + sc[c]) - 2.0f * acc[c];
      float P = fmaxf(u, 0.0f) * s32;  // bitwise = r7/r12 chain
      if (PASSB) {
        if ((P - GMAXF) < thrv) {  // sound screen
          int col = c0 + c;
          int idx = atomicAdd(&cnt[grow], 1);
          if (idx < CAP) {
            candP[(size_t)grow * CAP + idx] = P;
            candC[(size_t)grow * CAP + idx] = (unsigned short)col;
          }
        }
      } else {
        if (P < mn2) {
          if (P < mn1) { mn2 = mn1; mn1 = P; }
          else mn2 = P;
        }
      }
    }
    if (!PASSB) {
      if ((ci & 3) == 3) {  // 64-col cell complete (same granularity as r12)
        int cell = colseg * 16 + w * 4 + (ci >> 2);
        cellmin[(size_t)grow * 64 + cell] = make_float2(mn1, mn2);
        mn1 = mn2 = __builtin_inff();
      }
    }
  }
}

// ---------------- K4: thrP[row] = 16th-smallest of cellmin union + pad ----------------
__global__ __launch_bounds__(256) void thr_kernel(
    const float2* __restrict__ cellmin, float* __restrict__ thrP,
    int* __restrict__ cnt) {
  int row = (int)blockIdx.x * 256 + (int)threadIdx.x;
  const float2* cm = cellmin + (size_t)row * 64;
  float tv[16];
#pragma unroll
  for (int k = 0; k < 16; ++k) tv[k] = __builtin_inff();
  for (int i = 0; i < 64; ++i) {
    float2 v2 = cm[i];
#pragma unroll
    for (int j = 0; j < 2; ++j) {
      float v = j ? v2.y : v2.x;
      if (v < tv[15]) {
#pragma unroll
        for (int k = 15; k >= 1; --k) {
          bool ltk = v < tv[k], ltk1 = v < tv[k - 1];
          tv[k] = ltk ? (ltk1 ? tv[k - 1] : v) : tv[k];
        }
        if (v < tv[0]) tv[0] = v;
      }
    }
  }
  thrP[row] = tv[15] + GMINPAD;  // >= true 16th-smallest lq (provable)
  cnt[row] = 0;
}

// ---------------- K6: exact lq on candidates, (lq,col) sort -> outputs ----------------
__global__ __launch_bounds__(256) void select_kernel(
    const float* __restrict__ candP, const unsigned short* __restrict__ candC,
    const int* __restrict__ cnt, const float* __restrict__ q,
    float* __restrict__ e0, float* __restrict__ e1, float* __restrict__ lp) {
#pragma clang fp contract(off)
  int row = (int)blockIdx.x * 256 + (int)threadIdx.x;
  int b = row >> 12, n = row & (NN - 1);
  int c = cnt[row];
  if (c > CAP) c = CAP;
  const float* pb = candP + (size_t)row * CAP;
  const unsigned short* cb = candC + (size_t)row * CAP;
  const float* qrow = q + ((size_t)b * NN + n) * NN;
  float tv[16];
  int ti[16];
#pragma unroll
  for (int k = 0; k < 16; ++k) { tv[k] = __builtin_inff(); ti[k] = 0x7FFFFFFF; }
  for (int i = 0; i < c; ++i) {
    float P = pb[i];
    int col = (int)cb[i];
    float qv = qrow[col];
    float t1 = qv + 1e-8f;
    float l1 = (float)log((double)t1);  // correctly-rounded f32 log (r7-verified)
    float G = (float)log((double)(-l1));
    float lq = P - G;
    // sort by (lq, col): deterministic despite atomic append order; jax-stable
    bool lt15 = (lq < tv[15]) || (lq == tv[15] && col < ti[15]);
    if (lt15) {
#pragma unroll
      for (int k = 15; k >= 1; --k) {
        bool ltk = (lq < tv[k]) || (lq == tv[k] && col < ti[k]);
        bool ltk1 = (lq < tv[k - 1]) || (lq == tv[k - 1] && col < ti[k - 1]);
        tv[k] = ltk ? (ltk1 ? tv[k - 1] : lq) : tv[k];
        ti[k] = ltk ? (ltk1 ? ti[k - 1] : col) : ti[k];
      }
      bool lt0 = (lq < tv[0]) || (lq == tv[0] && col < ti[0]);
      if (lt0) { tv[0] = lq; ti[0] = col; }
    }
  }
  size_t o = (size_t)row * KK;
#pragma unroll
  for (int k = 0; k < KK; ++k) {
    lp[o + k] = -tv[k];
    e0[o + k] = (float)(ti[k] + b * NN);
    e1[o + k] = (float)(n + b * NN);
  }
}

extern "C" void kernel_launch(void* const* d_in, const int* in_sizes, int n_in,
                              void* d_out, int out_size, void* d_ws,
                              size_t ws_size, hipStream_t stream) {
  (void)in_sizes; (void)n_in; (void)out_size; (void)ws_size;
  const float* x = (const float*)d_in[0];
  // d_in[1] = A (unused placeholder)
  const float* W = (const float*)d_in[2];
  const float* bias = (const float*)d_in[3];
  const float* temp = (const float*)d_in[4];
  const float* q = (const float*)d_in[5];

  float* xe = (float*)d_out;                 // [4,4096,64]
  float* e0 = xe + (size_t)BATCH * NN * DE;  // edges row 0 (indices)
  float* e1 = e0 + (size_t)BATCH * NN * KK;  // edges row 1 (rows)
  float* lp = e1 + (size_t)BATCH * NN * KK;  // logprobs

  const int ROWS = BATCH * NN;  // 16384
  char* ws = (char*)d_ws;
  float* sq = (float*)ws;                       // 64 KB
  float* thrP = (float*)(ws + (64 << 10));      // 64 KB
  int* cnt = (int*)(ws + (128 << 10));          // 64 KB
  float* xeT = (float*)(ws + (192 << 10));      // 4 MB
  char* buf = ws + (192 << 10) + ((size_t)BATCH * DE * NN * 4);
  float2* cellmin = (float2*)buf;               // 8 MB (dead after thr)
  float* candP = (float*)buf;                   // aliases cellmin: 8 MB
  unsigned short* candC =
      (unsigned short*)(buf + (size_t)ROWS * CAP * 4);  // 4 MB
  // total ~16.2 MB <= 25.2 MB proven available

  embed_kernel<<<BATCH * NN / 4, 256, 0, stream>>>(x, W, bias, xe);
  sqnorm_kernel<<<ROWS / 256, 256, 0, stream>>>(xe, sq);
  transpose_kernel<<<ROWS / 256, 256, 0, stream>>>(xe, xeT);
  gemm_pass_kernel<false><<<(ROWS / 64) * 4, 256, 0, stream>>>(
      xe, xeT, sq, temp, cellmin, thrP, cnt, candP, candC);
  thr_kernel<<<ROWS / 256, 256, 0, stream>>>(cellmin, thrP, cnt);
  gemm_pass_kernel<true><<<(ROWS / 64) * 4, 256, 0, stream>>>(
      xe, xeT, sq, temp, cellmin, thrP, cnt, candP, candC);
  select_kernel<<<ROWS / 256, 256, 0, stream>>>(candP, candC, cnt, q, e0, e1,
                                                lp);
}

// Round 14
// 378.498 us; speedup vs baseline: 7.1137x; 7.1137x over previous
//
#include <hip/hip_runtime.h>
#include <hip/hip_bf16.h>
#include <math.h>

#define BATCH 4
#define NN 4096
#define DIN 128
#define DE 64
#define KK 16
#define CAP 512
#define GMAXF 2.9135f   // rigorous upper bound on f32 G = log(-log(q+1e-8))
#define GMINPAD 16.65f  // rigorous: G > -16.64 => lq < P + 16.64
#define SCRMARG 0.01f   // f32 compare slack
#define EPSA 0.5f       // rigorous bound on |P_mfma - P_golden| (est 0.13, 4x margin)

typedef __attribute__((ext_vector_type(8))) short bf16x8;    // 8 bf16 = 4 VGPR
typedef __attribute__((ext_vector_type(16))) float f32x16;   // MFMA 32x32 acc

// ---------------- K1: xe = x @ W + bias (r7-verified) + bf16 hi/lo split ----------------
__global__ __launch_bounds__(256) void embed_kernel(
    const float* __restrict__ x, const float* __restrict__ W,
    const float* __restrict__ bias, float* __restrict__ xe,
    __hip_bfloat16* __restrict__ xeH, __hip_bfloat16* __restrict__ xeL) {
#pragma clang fp contract(off)
  __shared__ float wl[DIN][DE];
  __shared__ float xs[4][DIN];
  int t = threadIdx.x;
  for (int i = t * 4; i < DIN * DE; i += 1024)
    *(float4*)&wl[i >> 6][i & 63] = *(const float4*)&W[i];
  {
    int rr = t >> 6, dd = (t & 63) * 2;
    const float* src = x + ((size_t)blockIdx.x * 4 + rr) * DIN + dd;
    xs[rr][dd] = src[0];
    xs[rr][dd + 1] = src[1];
  }
  __syncthreads();
  int w = t >> 6, lane = t & 63;
  float acc = 0.f;
#pragma unroll
  for (int d = 0; d < DIN; ++d)
    acc = __builtin_fmaf(xs[w][d], wl[d][lane], acc);  // sequential FMA chain
  float r32 = acc + bias[lane];
  size_t o = ((size_t)blockIdx.x * 4 + w) * DE + lane;
  xe[o] = r32;
  __hip_bfloat16 h = __float2bfloat16(r32);
  float hf = __bfloat162float(h);
  xeH[o] = h;
  xeL[o] = __float2bfloat16(r32 - hf);
}

// numpy pairwise sum (n=64, scalar 8-accumulator path) of squares (r7-verified)
static __device__ __forceinline__ float np_pairwise_sq64(const float* a) {
#pragma clang fp contract(off)
  float p[8];
#pragma unroll
  for (int j = 0; j < 8; ++j) { float v = a[j]; p[j] = v * v; }
#pragma unroll
  for (int i = 8; i < 64; i += 8)
#pragma unroll
    for (int j = 0; j < 8; ++j) { float v = a[i + j]; p[j] = p[j] + v * v; }
  return ((p[0] + p[1]) + (p[2] + p[3])) + ((p[4] + p[5]) + (p[6] + p[7]));
}

__global__ __launch_bounds__(256) void sqnorm_kernel(
    const float* __restrict__ xe, float* __restrict__ sq) {
  int row = blockIdx.x * 256 + threadIdx.x;
  sq[row] = np_pairwise_sq64(xe + (size_t)row * DE);
}

// ---------------- K3/K5: MFMA split-bf16 approximate-P pass ----------------
// Block = 128 rows x 256 cols, 4 waves (wave = 32 rows). gram~ = hi.hi+hi.lo+lo.hi
// via mfma_f32_32x32x16_bf16 (4 k-steps). D layout (HW-verified m74/m101):
// col = lane&31, row = (reg&3)+8*(reg>>2)+4*(lane>>5). A: row=lane&31,
// k=(lane>>5)*8+e; B: col=lane&31, same k-map (k-map errors cancel A vs B).
// PASSA: per-row min2 per 128-col half -> cellA. PASSB: screen + append col.
template <bool PASSB>
__global__ __launch_bounds__(256, 1) void mfma_pass_kernel(
    const __hip_bfloat16* __restrict__ xeH,
    const __hip_bfloat16* __restrict__ xeL, const float* __restrict__ sq,
    const float* __restrict__ temp, float2* __restrict__ cellA,
    const float* __restrict__ thrP, int* __restrict__ cnt,
    unsigned short* __restrict__ candC) {
  int t = threadIdx.x;
  int w = t >> 6, lane = t & 63;
  int l31 = lane & 31, h = lane >> 5;
  int bid = (int)blockIdx.x;
  int cb = bid & 15;          // 256-col block
  int rb = (bid >> 4) & 31;   // 128-row tile
  int b = bid >> 9;           // batch
  int gr0 = (b << 12) + rb * 128 + w * 32;  // wave row base (global)
  int arow = gr0 + l31;

  bf16x8 aH[4], aL[4];
  {
    const __hip_bfloat16* pH = xeH + (size_t)arow * DE + h * 8;
    const __hip_bfloat16* pL = xeL + (size_t)arow * DE + h * 8;
#pragma unroll
    for (int ks = 0; ks < 4; ++ks) {
      aH[ks] = *(const bf16x8*)(const void*)(pH + ks * 16);
      aL[ks] = *(const bf16x8*)(const void*)(pL + ks * 16);
    }
  }

  float sqr[16], thrx[16];
#pragma unroll
  for (int i = 0; i < 16; ++i) {
    int ri = (i & 3) + 8 * (i >> 2) + 4 * h;
    sqr[i] = sq[gr0 + ri];
    if (PASSB) thrx[i] = thrP[gr0 + ri] + (SCRMARG + EPSA + GMAXF);
  }
  float s32 = (float)exp(fmin(fmax((double)temp[0], -5.0), 5.0));

  float m1[16], m2[16];
#pragma unroll
  for (int i = 0; i < 16; ++i) { m1[i] = __builtin_inff(); m2[i] = __builtin_inff(); }

  for (int ct = 0; ct < 8; ++ct) {
    int colw = cb * 256 + ct * 32 + l31;  // col within batch
    bf16x8 bH[4], bL[4];
    {
      const __hip_bfloat16* pH = xeH + (size_t)((b << 12) + colw) * DE + h * 8;
      const __hip_bfloat16* pL = xeL + (size_t)((b << 12) + colw) * DE + h * 8;
#pragma unroll
      for (int ks = 0; ks < 4; ++ks) {
        bH[ks] = *(const bf16x8*)(const void*)(pH + ks * 16);
        bL[ks] = *(const bf16x8*)(const void*)(pL + ks * 16);
      }
    }
    float sqc = sq[(b << 12) + colw];

    f32x16 acc = {};
#pragma unroll
    for (int ks = 0; ks < 4; ++ks) {
      acc = __builtin_amdgcn_mfma_f32_32x32x16_bf16(aH[ks], bH[ks], acc, 0, 0, 0);
      acc = __builtin_amdgcn_mfma_f32_32x32x16_bf16(aH[ks], bL[ks], acc, 0, 0, 0);
      acc = __builtin_amdgcn_mfma_f32_32x32x16_bf16(aL[ks], bH[ks], acc, 0, 0, 0);
    }

#pragma unroll
    for (int i = 0; i < 16; ++i) {
      float u = (sqr[i] + sqc) - 2.0f * acc[i];
      float P = fmaxf(u, 0.0f) * s32;  // approx: |P - P_golden| <= EPSA
      if (PASSB) {
        if (P < thrx[i]) {
          int ri = (i & 3) + 8 * (i >> 2) + 4 * h;
          int grow = gr0 + ri;
          int idx = atomicAdd(&cnt[grow], 1);
          if (idx < CAP) candC[(size_t)grow * CAP + idx] = (unsigned short)colw;
        }
      } else {
        if (P < m2[i]) {
          if (P < m1[i]) { m2[i] = m1[i]; m1[i] = P; } else m2[i] = P;
        }
      }
    }

    if (!PASSB && (ct == 3 || ct == 7)) {
      // cross-lane min2 merge over the 32 lanes sharing h, then store + reset
#pragma unroll
      for (int s = 1; s <= 16; s <<= 1) {
#pragma unroll
        for (int i = 0; i < 16; ++i) {
          float o1 = __shfl_xor(m1[i], s);
          float o2 = __shfl_xor(m2[i], s);
          float n1 = fminf(m1[i], o1);
          float n2 = fminf(fmaxf(m1[i], o1), fminf(m2[i], o2));
          m1[i] = n1;
          m2[i] = n2;
        }
      }
      if (l31 == 0) {
#pragma unroll
        for (int i = 0; i < 16; ++i) {
          int ri = (i & 3) + 8 * (i >> 2) + 4 * h;
          cellA[(size_t)(gr0 + ri) * 32 + cb * 2 + (ct >> 2)] =
              make_float2(m1[i], m2[i]);
        }
      }
#pragma unroll
      for (int i = 0; i < 16; ++i) { m1[i] = __builtin_inff(); m2[i] = __builtin_inff(); }
    }
  }
}

// ---------------- K4: thrP = 16th-smallest of cellA union + pads; zero cnt ----------------
__global__ __launch_bounds__(256) void thr_kernel(
    const float2* __restrict__ cellA, float* __restrict__ thrP,
    int* __restrict__ cnt) {
  int row = (int)blockIdx.x * 256 + (int)threadIdx.x;
  const float2* cm = cellA + (size_t)row * 32;
  float tv[16];
#pragma unroll
  for (int k = 0; k < 16; ++k) tv[k] = __builtin_inff();
  for (int i = 0; i < 32; ++i) {
    float2 v2 = cm[i];
#pragma unroll
    for (int j = 0; j < 2; ++j) {
      float v = j ? v2.y : v2.x;
      if (v < tv[15]) {
#pragma unroll
        for (int k = 15; k >= 1; --k) {
          bool ltk = v < tv[k], ltk1 = v < tv[k - 1];
          tv[k] = ltk ? (ltk1 ? tv[k - 1] : v) : tv[k];
        }
        if (v < tv[0]) tv[0] = v;
      }
    }
  }
  thrP[row] = tv[15] + (EPSA + GMINPAD);  // provable >= true 16th lq
  cnt[row] = 0;
}

// ---------------- K6: exact golden P + exact G on candidates -> outputs ----------------
__global__ __launch_bounds__(256, 1) void select_kernel(
    const unsigned short* __restrict__ candC, const int* __restrict__ cnt,
    const float* __restrict__ xe, const float* __restrict__ sq,
    const float* __restrict__ temp, const float* __restrict__ q,
    float* __restrict__ e0, float* __restrict__ e1, float* __restrict__ lp) {
#pragma clang fp contract(off)
  int row = (int)blockIdx.x * 256 + (int)threadIdx.x;
  int b = row >> 12, n = row & (NN - 1);
  float s32 = (float)exp(fmin(fmax((double)temp[0], -5.0), 5.0));
  float sqr = sq[row];
  const float* xb = xe + ((size_t)(b << 12)) * DE;
  const float* xr = xb + (size_t)n * DE;
  const float* sqb = sq + (b << 12);
  const float* qrow = q + ((size_t)b * NN + n) * NN;
  float tv[16];
  int ti[16];
#pragma unroll
  for (int k = 0; k < 16; ++k) { tv[k] = __builtin_inff(); ti[k] = 0x7FFFFFFF; }
  int c = cnt[row];
  bool overflow = c > CAP;
  int lim = overflow ? NN : c;
  for (int i = 0; i < lim; ++i) {
    int col = overflow ? i : (int)candC[(size_t)row * CAP + i];
    // exact golden P: sequential FMA d=0..63 (r7/r12-verified order)
    const float* xc = xb + (size_t)col * DE;
    float acc = 0.f;
#pragma unroll
    for (int d = 0; d < DE; ++d) acc = __builtin_fmaf(xr[d], xc[d], acc);
    float u = (sqr + sqb[col]) - 2.0f * acc;
    float P = fmaxf(u, 0.0f) * s32;
    if (P - GMAXF >= tv[15]) continue;  // sound: lq >= P - GMAXF
    float qv = qrow[col];
    float t1 = qv + 1e-8f;
    float l1 = (float)log((double)t1);  // correctly-rounded f32 log (r7-verified)
    float G = (float)log((double)(-l1));
    float lq = P - G;
    bool lt15 = (lq < tv[15]) || (lq == tv[15] && col < ti[15]);
    if (lt15) {
#pragma unroll
      for (int k = 15; k >= 1; --k) {
        bool ltk = (lq < tv[k]) || (lq == tv[k] && col < ti[k]);
        bool ltk1 = (lq < tv[k - 1]) || (lq == tv[k - 1] && col < ti[k - 1]);
        tv[k] = ltk ? (ltk1 ? tv[k - 1] : lq) : tv[k];
        ti[k] = ltk ? (ltk1 ? ti[k - 1] : col) : ti[k];
      }
      bool lt0 = (lq < tv[0]) || (lq == tv[0] && col < ti[0]);
      if (lt0) { tv[0] = lq; ti[0] = col; }
    }
  }
  size_t o = (size_t)row * KK;
#pragma unroll
  for (int k = 0; k < KK; ++k) {
    lp[o + k] = -tv[k];
    e0[o + k] = (float)(ti[k] + b * NN);
    e1[o + k] = (float)(n + b * NN);
  }
}

extern "C" void kernel_launch(void* const* d_in, const int* in_sizes, int n_in,
                              void* d_out, int out_size, void* d_ws,
                              size_t ws_size, hipStream_t stream) {
  (void)in_sizes; (void)n_in; (void)out_size; (void)ws_size;
  const float* x = (const float*)d_in[0];
  // d_in[1] = A (unused placeholder)
  const float* W = (const float*)d_in[2];
  const float* bias = (const float*)d_in[3];
  const float* temp = (const float*)d_in[4];
  const float* q = (const float*)d_in[5];

  float* xe = (float*)d_out;                 // [4,4096,64]
  float* e0 = xe + (size_t)BATCH * NN * DE;  // edges row 0 (indices)
  float* e1 = e0 + (size_t)BATCH * NN * KK;  // edges row 1 (rows)
  float* lp = e1 + (size_t)BATCH * NN * KK;  // logprobs

  const int ROWS = BATCH * NN;  // 16384
  char* ws = (char*)d_ws;
  float* sq = (float*)ws;                                  // 64 KB
  float* thrP = (float*)(ws + (64 << 10));                 // 64 KB
  int* cnt = (int*)(ws + (128 << 10));                     // 64 KB
  float2* cellA = (float2*)(ws + (192 << 10));             // 16384*32*8 = 4 MB
  char* p = ws + (192 << 10) + (size_t)ROWS * 32 * 8;
  __hip_bfloat16* xeH = (__hip_bfloat16*)p;                // 2 MB
  __hip_bfloat16* xeL = (__hip_bfloat16*)(p + (size_t)ROWS * DE * 2);  // 2 MB
  unsigned short* candC =
      (unsigned short*)(p + 2 * (size_t)ROWS * DE * 2);    // 16384*512*2 = 16.8 MB
  // total ~25.0 MB <= 25.36 MB proven available (r12 layout ran correctly)

  embed_kernel<<<BATCH * NN / 4, 256, 0, stream>>>(x, W, bias, xe, xeH, xeL);
  sqnorm_kernel<<<ROWS / 256, 256, 0, stream>>>(xe, sq);
  mfma_pass_kernel<false><<<BATCH * 32 * 16, 256, 0, stream>>>(
      xeH, xeL, sq, temp, cellA, thrP, cnt, candC);
  thr_kernel<<<ROWS / 256, 256, 0, stream>>>(cellA, thrP, cnt);
  mfma_pass_kernel<true><<<BATCH * 32 * 16, 256, 0, stream>>>(
      xeH, xeL, sq, temp, cellA, thrP, cnt, candC);
  select_kernel<<<ROWS / 256, 256, 0, stream>>>(candC, cnt, xe, sq, temp, q, e0,
                                                e1, lp);
}

// Round 15
// 370.804 us; speedup vs baseline: 7.2613x; 1.0207x over previous
//
#include <hip/hip_runtime.h>
#include <hip/hip_bf16.h>
#include <math.h>

#define BATCH 4
#define NN 4096
#define DIN 128
#define DE 64
#define KK 16
#define CAP 512
#define GMAXF 2.9135f   // rigorous upper bound on f32 G = log(-log(q+1e-8))
#define GMINPAD 16.65f  // rigorous: G > -16.64 => lq < P + 16.64
#define SCRMARG 0.01f   // f32 compare slack
#define EPSA 0.5f       // rigorous bound on |P_mfma - P_golden| (est 0.13, 4x margin)

typedef __attribute__((ext_vector_type(8))) short bf16x8;    // 8 bf16 = 4 VGPR
typedef __attribute__((ext_vector_type(16))) float f32x16;   // MFMA 32x32 acc

// ---------------- K1: xe = x @ W + bias (r7-verified) + bf16 hi/lo split ----------------
__global__ __launch_bounds__(256) void embed_kernel(
    const float* __restrict__ x, const float* __restrict__ W,
    const float* __restrict__ bias, float* __restrict__ xe,
    __hip_bfloat16* __restrict__ xeH, __hip_bfloat16* __restrict__ xeL) {
#pragma clang fp contract(off)
  __shared__ float wl[DIN][DE];
  __shared__ float xs[4][DIN];
  int t = threadIdx.x;
  for (int i = t * 4; i < DIN * DE; i += 1024)
    *(float4*)&wl[i >> 6][i & 63] = *(const float4*)&W[i];
  {
    int rr = t >> 6, dd = (t & 63) * 2;
    const float* src = x + ((size_t)blockIdx.x * 4 + rr) * DIN + dd;
    xs[rr][dd] = src[0];
    xs[rr][dd + 1] = src[1];
  }
  __syncthreads();
  int w = t >> 6, lane = t & 63;
  float acc = 0.f;
#pragma unroll
  for (int d = 0; d < DIN; ++d)
    acc = __builtin_fmaf(xs[w][d], wl[d][lane], acc);  // sequential FMA chain
  float r32 = acc + bias[lane];
  size_t o = ((size_t)blockIdx.x * 4 + w) * DE + lane;
  xe[o] = r32;
  __hip_bfloat16 h = __float2bfloat16(r32);
  float hf = __bfloat162float(h);
  xeH[o] = h;
  xeL[o] = __float2bfloat16(r32 - hf);
}

// numpy pairwise sum (n=64, scalar 8-accumulator path) of squares (r7-verified)
static __device__ __forceinline__ float np_pairwise_sq64(const float* a) {
#pragma clang fp contract(off)
  float p[8];
#pragma unroll
  for (int j = 0; j < 8; ++j) { float v = a[j]; p[j] = v * v; }
#pragma unroll
  for (int i = 8; i < 64; i += 8)
#pragma unroll
    for (int j = 0; j < 8; ++j) { float v = a[i + j]; p[j] = p[j] + v * v; }
  return ((p[0] + p[1]) + (p[2] + p[3])) + ((p[4] + p[5]) + (p[6] + p[7]));
}

__global__ __launch_bounds__(256) void sqnorm_kernel(
    const float* __restrict__ xe, float* __restrict__ sq) {
  int row = blockIdx.x * 256 + threadIdx.x;
  sq[row] = np_pairwise_sq64(xe + (size_t)row * DE);
}

// ---------------- K3/K5: MFMA split-bf16 approximate pass (u-space) ----------------
// Block = 128 rows x 256 cols, 4 waves. Fragment layout = r14-verified.
// 3 independent acc chains (HH,HL,LH) summed at tile end; B double-buffered.
// PASSA: per-row min2 of u over the block's 256 cols -> cellA[row][cb].
// PASSB: screen u < uthr[row] -> append col.
template <bool PASSB>
__global__ __launch_bounds__(256, 1) void mfma_pass_kernel(
    const __hip_bfloat16* __restrict__ xeH,
    const __hip_bfloat16* __restrict__ xeL, const float* __restrict__ sq,
    float2* __restrict__ cellA, const float* __restrict__ uthr,
    int* __restrict__ cnt, unsigned short* __restrict__ candC) {
  int t = threadIdx.x;
  int w = t >> 6, lane = t & 63;
  int l31 = lane & 31, h = lane >> 5;
  int bid = (int)blockIdx.x;
  int cb = bid & 15;          // 256-col block
  int rb = (bid >> 4) & 31;   // 128-row tile
  int b = bid >> 9;           // batch
  int gr0 = (b << 12) + rb * 128 + w * 32;  // wave row base (global)
  int arow = gr0 + l31;

  bf16x8 aH[4], aL[4];
  {
    const __hip_bfloat16* pH = xeH + (size_t)arow * DE + h * 8;
    const __hip_bfloat16* pL = xeL + (size_t)arow * DE + h * 8;
#pragma unroll
    for (int ks = 0; ks < 4; ++ks) {
      aH[ks] = *(const bf16x8*)(const void*)(pH + ks * 16);
      aL[ks] = *(const bf16x8*)(const void*)(pL + ks * 16);
    }
  }

  float sqr[16], thrx[16];
#pragma unroll
  for (int i = 0; i < 16; ++i) {
    int ri = (i & 3) + 8 * (i >> 2) + 4 * h;
    sqr[i] = sq[gr0 + ri];
    if (PASSB) thrx[i] = uthr[gr0 + ri];
  }

  float m1[16], m2[16];
#pragma unroll
  for (int i = 0; i < 16; ++i) { m1[i] = __builtin_inff(); m2[i] = __builtin_inff(); }

  bf16x8 BH[2][4], BL[2][4];
  float SQC[2];
#define LOADB(CT, SL)                                                        \
  {                                                                          \
    int colw_ = cb * 256 + (CT)*32 + l31;                                    \
    const __hip_bfloat16* pH_ = xeH + (size_t)((b << 12) + colw_) * DE + h * 8; \
    const __hip_bfloat16* pL_ = xeL + (size_t)((b << 12) + colw_) * DE + h * 8; \
    _Pragma("unroll") for (int ks = 0; ks < 4; ++ks) {                       \
      BH[SL][ks] = *(const bf16x8*)(const void*)(pH_ + ks * 16);             \
      BL[SL][ks] = *(const bf16x8*)(const void*)(pL_ + ks * 16);             \
    }                                                                        \
    SQC[SL] = sq[(b << 12) + colw_];                                         \
  }

  LOADB(0, 0)
#pragma unroll
  for (int ct = 0; ct < 8; ++ct) {
    int cur = ct & 1;
    if (ct < 7) LOADB(ct + 1, cur ^ 1)

    f32x16 aHH = {}, aHL = {}, aLH = {};
#pragma unroll
    for (int ks = 0; ks < 4; ++ks) {
      aHH = __builtin_amdgcn_mfma_f32_32x32x16_bf16(aH[ks], BH[cur][ks], aHH, 0, 0, 0);
      aHL = __builtin_amdgcn_mfma_f32_32x32x16_bf16(aH[ks], BL[cur][ks], aHL, 0, 0, 0);
      aLH = __builtin_amdgcn_mfma_f32_32x32x16_bf16(aL[ks], BH[cur][ks], aLH, 0, 0, 0);
    }

    float sqc = SQC[cur];
#pragma unroll
    for (int i = 0; i < 16; ++i) {
      float g = (aHH[i] + aHL[i]) + aLH[i];
      float u = (sqr[i] + sqc) - 2.0f * g;
      if (PASSB) {
        if (u < thrx[i]) {
          int ri = (i & 3) + 8 * (i >> 2) + 4 * h;
          int grow = gr0 + ri;
          int colw = cb * 256 + ct * 32 + l31;
          int idx = atomicAdd(&cnt[grow], 1);
          if (idx < CAP) candC[(size_t)grow * CAP + idx] = (unsigned short)colw;
        }
      } else {
        // branchless min2: m2' = min(max(u,m1),m2); m1' = min(u,m1)
        float nm2 = fminf(fmaxf(u, m1[i]), m2[i]);
        m1[i] = fminf(u, m1[i]);
        m2[i] = nm2;
      }
    }
  }
#undef LOADB

  if (!PASSB) {
    // cross-lane min2 merge over the 32 lanes sharing h
#pragma unroll
    for (int s = 1; s <= 16; s <<= 1) {
#pragma unroll
      for (int i = 0; i < 16; ++i) {
        float o1 = __shfl_xor(m1[i], s);
        float o2 = __shfl_xor(m2[i], s);
        float n1 = fminf(m1[i], o1);
        float n2 = fminf(fmaxf(m1[i], o1), fminf(m2[i], o2));
        m1[i] = n1;
        m2[i] = n2;
      }
    }
    if (l31 == 0) {
#pragma unroll
      for (int i = 0; i < 16; ++i) {
        int ri = (i & 3) + 8 * (i >> 2) + 4 * h;
        cellA[(size_t)(gr0 + ri) * 16 + cb] = make_float2(m1[i], m2[i]);
      }
    }
  }
}

// ---------------- K4: uthr[row] from 16th-smallest u of cellA union ----------------
__global__ __launch_bounds__(256) void thr_kernel(
    const float2* __restrict__ cellA, const float* __restrict__ temp,
    float* __restrict__ uthr, int* __restrict__ cnt) {
  int row = (int)blockIdx.x * 256 + (int)threadIdx.x;
  float s32 = (float)exp(fmin(fmax((double)temp[0], -5.0), 5.0));
  const float2* cm = cellA + (size_t)row * 16;
  float tv[16];
#pragma unroll
  for (int k = 0; k < 16; ++k) tv[k] = __builtin_inff();
  for (int i = 0; i < 16; ++i) {
    float2 v2 = cm[i];
#pragma unroll
    for (int j = 0; j < 2; ++j) {
      float v = j ? v2.y : v2.x;
      if (v < tv[15]) {
#pragma unroll
        for (int k = 15; k >= 1; --k) {
          bool ltk = v < tv[k], ltk1 = v < tv[k - 1];
          tv[k] = ltk ? (ltk1 ? tv[k - 1] : v) : tv[k];
        }
        if (v < tv[0]) tv[0] = v;
      }
    }
  }
  // P16~ = fmax(u16,0)*s32; thr_lq = P16~+EPSA+GMINPAD >= true 16th lq;
  // screen-T = thr_lq+SCRMARG+EPSA+GMAXF; back to u-space, round up (sound).
  float P16 = fmaxf(tv[15], 0.f) * s32;
  float T = P16 + (EPSA + GMINPAD + SCRMARG + EPSA + GMAXF);
  double ud = (double)T / (double)s32;
  uthr[row] = (float)(ud * 1.000002 + 1e-6);
  cnt[row] = 0;
}

// ---------------- K6: exact golden P + exact G on candidates -> outputs ----------------
__global__ __launch_bounds__(256, 1) void select_kernel(
    const unsigned short* __restrict__ candC, const int* __restrict__ cnt,
    const float* __restrict__ xe, const float* __restrict__ sq,
    const float* __restrict__ temp, const float* __restrict__ q,
    float* __restrict__ e0, float* __restrict__ e1, float* __restrict__ lp) {
#pragma clang fp contract(off)
  int row = (int)blockIdx.x * 256 + (int)threadIdx.x;
  int b = row >> 12, n = row & (NN - 1);
  float s32 = (float)exp(fmin(fmax((double)temp[0], -5.0), 5.0));
  float sqr = sq[row];
  const float* xb = xe + ((size_t)(b << 12)) * DE;
  const float* xr = xb + (size_t)n * DE;
  const float* sqb = sq + (b << 12);
  const float* qrow = q + ((size_t)b * NN + n) * NN;
  float tv[16];
  int ti[16];
#pragma unroll
  for (int k = 0; k < 16; ++k) { tv[k] = __builtin_inff(); ti[k] = 0x7FFFFFFF; }
  int c = cnt[row];
  bool overflow = c > CAP;
  int lim = overflow ? NN : c;
  for (int i = 0; i < lim; ++i) {
    int col = overflow ? i : (int)candC[(size_t)row * CAP + i];
    // exact golden P: sequential FMA d=0..63 (r7/r12-verified order)
    const float* xc = xb + (size_t)col * DE;
    float acc = 0.f;
#pragma unroll
    for (int d = 0; d < DE; ++d) acc = __builtin_fmaf(xr[d], xc[d], acc);
    float u = (sqr + sqb[col]) - 2.0f * acc;
    float P = fmaxf(u, 0.0f) * s32;
    if (P - GMAXF >= tv[15]) continue;  // sound: lq >= P - GMAXF
    float qv = qrow[col];
    float t1 = qv + 1e-8f;
    float l1 = (float)log((double)t1);  // correctly-rounded f32 log (r7-verified)
    float G = (float)log((double)(-l1));
    float lq = P - G;
    bool lt15 = (lq < tv[15]) || (lq == tv[15] && col < ti[15]);
    if (lt15) {
#pragma unroll
      for (int k = 15; k >= 1; --k) {
        bool ltk = (lq < tv[k]) || (lq == tv[k] && col < ti[k]);
        bool ltk1 = (lq < tv[k - 1]) || (lq == tv[k - 1] && col < ti[k - 1]);
        tv[k] = ltk ? (ltk1 ? tv[k - 1] : lq) : tv[k];
        ti[k] = ltk ? (ltk1 ? ti[k - 1] : col) : ti[k];
      }
      bool lt0 = (lq < tv[0]) || (lq == tv[0] && col < ti[0]);
      if (lt0) { tv[0] = lq; ti[0] = col; }
    }
  }
  size_t o = (size_t)row * KK;
#pragma unroll
  for (int k = 0; k < KK; ++k) {
    lp[o + k] = -tv[k];
    e0[o + k] = (float)(ti[k] + b * NN);
    e1[o + k] = (float)(n + b * NN);
  }
}

extern "C" void kernel_launch(void* const* d_in, const int* in_sizes, int n_in,
                              void* d_out, int out_size, void* d_ws,
                              size_t ws_size, hipStream_t stream) {
  (void)in_sizes; (void)n_in; (void)out_size; (void)ws_size;
  const float* x = (const float*)d_in[0];
  // d_in[1] = A (unused placeholder)
  const float* W = (const float*)d_in[2];
  const float* bias = (const float*)d_in[3];
  const float* temp = (const float*)d_in[4];
  const float* q = (const float*)d_in[5];

  float* xe = (float*)d_out;                 // [4,4096,64]
  float* e0 = xe + (size_t)BATCH * NN * DE;  // edges row 0 (indices)
  float* e1 = e0 + (size_t)BATCH * NN * KK;  // edges row 1 (rows)
  float* lp = e1 + (size_t)BATCH * NN * KK;  // logprobs

  const int ROWS = BATCH * NN;  // 16384
  char* ws = (char*)d_ws;
  float* sq = (float*)ws;                                  // 64 KB
  float* uthr = (float*)(ws + (64 << 10));                 // 64 KB
  int* cnt = (int*)(ws + (128 << 10));                     // 64 KB
  float2* cellA = (float2*)(ws + (192 << 10));             // 16384*16*8 = 2 MB
  char* p = ws + (192 << 10) + (size_t)ROWS * 16 * 8;
  __hip_bfloat16* xeH = (__hip_bfloat16*)p;                // 2 MB
  __hip_bfloat16* xeL = (__hip_bfloat16*)(p + (size_t)ROWS * DE * 2);  // 2 MB
  unsigned short* candC =
      (unsigned short*)(p + 2 * (size_t)ROWS * DE * 2);    // 16384*512*2 = 16.8 MB
  // total ~23 MB <= proven available

  embed_kernel<<<BATCH * NN / 4, 256, 0, stream>>>(x, W, bias, xe, xeH, xeL);
  sqnorm_kernel<<<ROWS / 256, 256, 0, stream>>>(xe, sq);
  mfma_pass_kernel<false><<<BATCH * 32 * 16, 256, 0, stream>>>(
      xeH, xeL, sq, cellA, uthr, cnt, candC);
  thr_kernel<<<ROWS / 256, 256, 0, stream>>>(cellA, temp, uthr, cnt);
  mfma_pass_kernel<true><<<BATCH * 32 * 16, 256, 0, stream>>>(
      xeH, xeL, sq, cellA, uthr, cnt, candC);
  select_kernel<<<ROWS / 256, 256, 0, stream>>>(candC, cnt, xe, sq, temp, q, e0,
                                                e1, lp);
}